// Round 6
// baseline (202.755 us; speedup 1.0000x reference)
//
#include <hip/hip_runtime.h>
#include <hip/hip_fp16.h>

typedef _Float16 half8 __attribute__((ext_vector_type(8)));
typedef float   float4v __attribute__((ext_vector_type(4)));
typedef float   float16v __attribute__((ext_vector_type(16)));

#define S_LEN 4096
#define NBATCH 4
#define NCHUNK 8
// ws layout in halves:
#define WS_QH  0          // 16384*64  (token-major [B*S][64], pre-scaled by 0.125)
#define WS_KH  1048576    // 16384*64
#define WS_VT  2097152    // 4*128*4096 (per-batch transposed [128][S])
#define WS_L   4194304    // float[16384] row sum-of-exp accumulators

// ---------------- kernel 1: QKV projection, frags direct from global ----------
// grid 1024 blocks x 256 thr. Block = 16 tokens; wave w = 64 out-channels:
// w0 -> Q (scaled 0.125), w1 -> K, w2 -> V[0:64), w3 -> V[64:128).
// Also zeroes out/lbuf (atomic accumulators for flash).
__global__ __launch_bounds__(256) void qkv_proj_kernel(const float* __restrict__ x,
                                                       const float* __restrict__ Wq,
                                                       const float* __restrict__ Wk,
                                                       const float* __restrict__ Wv,
                                                       _Float16* __restrict__ Qh,
                                                       _Float16* __restrict__ Kh,
                                                       _Float16* __restrict__ Vt,
                                                       float4v* __restrict__ out4,
                                                       float4v* __restrict__ l4) {
    const int t = threadIdx.x, blk = blockIdx.x;
    // zero the atomic accumulators (524288 float4 / 1024 blocks = 512/blk)
    out4[blk * 512 + t]       = (float4v){0.f, 0.f, 0.f, 0.f};
    out4[blk * 512 + 256 + t] = (float4v){0.f, 0.f, 0.f, 0.f};
    if (t < 4) l4[blk * 4 + t] = (float4v){0.f, 0.f, 0.f, 0.f};

    const int w = t >> 6, lane = t & 63, quad = lane >> 4, n16 = lane & 15;
    const int token0 = blk * 16;

    // A-frags: x rows token0+n16, k = c*32 + quad*8 + j  (fp32 -> fp16 inline)
    const float* xr = x + (size_t)(token0 + n16) * 128;
    half8 a[4];
    for (int c = 0; c < 4; ++c) {
        float4v f0 = *(const float4v*)&xr[c * 32 + quad * 8];
        float4v f1 = *(const float4v*)&xr[c * 32 + quad * 8 + 4];
        half8 h;
        h[0] = (_Float16)f0[0]; h[1] = (_Float16)f0[1];
        h[2] = (_Float16)f0[2]; h[3] = (_Float16)f0[3];
        h[4] = (_Float16)f1[0]; h[5] = (_Float16)f1[1];
        h[6] = (_Float16)f1[2]; h[7] = (_Float16)f1[3];
        a[c] = h;
    }

    const float* Wsrc = (w == 0) ? Wq : (w == 1) ? Wk : Wv;
    const int rowoff = (w == 3) ? 64 : 0;

    float4v acc[4];
    for (int nb = 0; nb < 4; ++nb) acc[nb] = (float4v){0.f, 0.f, 0.f, 0.f};

    for (int c = 0; c < 4; ++c) {
        for (int nb = 0; nb < 4; ++nb) {
            const float* wr = Wsrc + (size_t)(rowoff + nb * 16 + n16) * 128 + c * 32 + quad * 8;
            float4v f0 = *(const float4v*)wr;
            float4v f1 = *(const float4v*)(wr + 4);
            half8 bf;
            bf[0] = (_Float16)f0[0]; bf[1] = (_Float16)f0[1];
            bf[2] = (_Float16)f0[2]; bf[3] = (_Float16)f0[3];
            bf[4] = (_Float16)f1[0]; bf[5] = (_Float16)f1[1];
            bf[6] = (_Float16)f1[2]; bf[7] = (_Float16)f1[3];
            acc[nb] = __builtin_amdgcn_mfma_f32_16x16x32_f16(a[c], bf, acc[nb], 0, 0, 0);
        }
    }

    // C layout: col = n16 (out-channel), row = quad*4 + r (token)
    if (w == 0) {
        for (int nb = 0; nb < 4; ++nb)
            for (int r = 0; r < 4; ++r)
                Qh[(size_t)(token0 + quad * 4 + r) * 64 + nb * 16 + n16] =
                    (_Float16)(acc[nb][r] * 0.125f);   // fold score scale into Q (exact)
    } else if (w == 1) {
        for (int nb = 0; nb < 4; ++nb)
            for (int r = 0; r < 4; ++r)
                Kh[(size_t)(token0 + quad * 4 + r) * 64 + nb * 16 + n16] = (_Float16)acc[nb][r];
    } else {
        for (int nb = 0; nb < 4; ++nb) {
            int vc = rowoff + nb * 16 + n16;
            for (int r = 0; r < 4; ++r) {
                int tok = token0 + quad * 4 + r;
                int b = tok >> 12, s = tok & 4095;
                Vt[((size_t)b * 128 + vc) * S_LEN + s] = (_Float16)acc[nb][r];
            }
        }
    }
}

// ---------------- kernel 2: flash attention, 32x32 MFMA, K direct-from-global -
// grid (S/128, NCHUNK, B) = (32,8,4), 256 thr (4 waves), LDS 36KB.
// Wave w owns 32 q rows (qt*128 + w*32). K B-frags come straight from global
// (L2-hot); V staged in LDS (shared by 4 waves); P round-trips wave-private LDS.
// Softmax: Q pre-scaled, p = exp(S-4) = exp2(S*log2e - 4*log2e); partial (O,l)
// exactly additive across chunks -> fp32 HW atomics.
// 32x32x16 layouts: A m=lane&31,k=(lane>>5)*8+j ; B same with n ; C/D col=lane&31,
// row=(r&3)+8*(r>>2)+4*(lane>>5)  [verified m74/m101 + R5 pass]
__global__ __launch_bounds__(256, 3) void flash_kernel(const _Float16* __restrict__ Qh,
                                                       const _Float16* __restrict__ Kh,
                                                       const _Float16* __restrict__ Vt,
                                                       float* __restrict__ out,
                                                       float* __restrict__ lbuf) {
    __shared__ _Float16 Vs[128 * 72];       // V^T tile [128ch][64key], padded
    __shared__ _Float16 Ps[4][32 * 72];     // per-wave P [32q][64key], padded

    const int t = threadIdx.x;
    const int qt = blockIdx.x, chunk = blockIdx.y, b = blockIdx.z;
    const int w = t >> 6, lane = t & 63, l32 = lane & 31, hi = lane >> 5;

    const size_t q0 = (size_t)b * S_LEN + qt * 128 + w * 32;
    half8 aQ[4];
    for (int ks = 0; ks < 4; ++ks)
        aQ[ks] = *(const half8*)&Qh[(q0 + l32) * 64 + ks * 16 + hi * 8];

    float16v O[4];
    for (int vb = 0; vb < 4; ++vb)
        for (int r = 0; r < 16; ++r) O[vb][r] = 0.f;
    float lsum[16];
    for (int r = 0; r < 16; ++r) lsum[r] = 0.f;

    const _Float16* Kb = Kh + (size_t)b * S_LEN * 64;
    const _Float16* Vb = Vt + (size_t)b * 128 * S_LEN;

    const int kt0 = chunk * (S_LEN / 64 / NCHUNK);
    const int kt1 = kt0 + (S_LEN / 64 / NCHUNK);

    for (int kt = kt0; kt < kt1; ++kt) {
        __syncthreads();   // previous V tile fully consumed
        for (int i = 0; i < 4; ++i) {
            int idx = t + i * 256, row = idx >> 3, c8 = idx & 7;
            *(half8*)&Vs[row * 72 + c8 * 8] =
                *(const half8*)&Vb[(size_t)row * S_LEN + kt * 64 + c8 * 8];
        }
        __syncthreads();

        // QK^T: S[32q x 64key] as 2 C-tiles; K frags direct from global (L2)
        for (int knb = 0; knb < 2; ++knb) {
            const _Float16* kp = Kb + (size_t)(kt * 64 + knb * 32 + l32) * 64;
            half8 bK0 = *(const half8*)&kp[hi * 8];
            half8 bK1 = *(const half8*)&kp[16 + hi * 8];
            half8 bK2 = *(const half8*)&kp[32 + hi * 8];
            half8 bK3 = *(const half8*)&kp[48 + hi * 8];
            float16v S;
            for (int r = 0; r < 16; ++r) S[r] = 0.f;
            S = __builtin_amdgcn_mfma_f32_32x32x16_f16(aQ[0], bK0, S, 0, 0, 0);
            S = __builtin_amdgcn_mfma_f32_32x32x16_f16(aQ[1], bK1, S, 0, 0, 0);
            S = __builtin_amdgcn_mfma_f32_32x32x16_f16(aQ[2], bK2, S, 0, 0, 0);
            S = __builtin_amdgcn_mfma_f32_32x32x16_f16(aQ[3], bK3, S, 0, 0, 0);
            for (int r = 0; r < 16; ++r) {
                float p = exp2f(fmaf(S[r], 1.44269504f, -5.77078016f));
                lsum[r] += p;
                int row = (r & 3) + 8 * (r >> 2) + 4 * hi;
                Ps[w][row * 72 + knb * 32 + l32] = (_Float16)p;   // wave-private
            }
        }
        // wave-private Ps RAW fence (no cross-wave barrier needed)
        asm volatile("s_waitcnt lgkmcnt(0)" ::: "memory");

        // PV: O[32q x 128v] as 4 C-tiles
        half8 aP[4];
        for (int kb = 0; kb < 4; ++kb)
            aP[kb] = *(const half8*)&Ps[w][l32 * 72 + kb * 16 + hi * 8];
        for (int vb = 0; vb < 4; ++vb)
            for (int kb = 0; kb < 4; ++kb) {
                half8 bV = *(const half8*)&Vs[(vb * 32 + l32) * 72 + kb * 16 + hi * 8];
                O[vb] = __builtin_amdgcn_mfma_f32_32x32x16_f16(aP[kb], bV, O[vb], 0, 0, 0);
            }
    }

    // reduce row sums across the 32 col-lanes of each half-wave
    for (int m = 1; m < 32; m <<= 1)
        for (int r = 0; r < 16; ++r)
            lsum[r] += __shfl_xor(lsum[r], m);

    const int qbase = qt * 128 + w * 32;
    if (l32 == 0)
        for (int r = 0; r < 16; ++r) {
            int row = (r & 3) + 8 * (r >> 2) + 4 * hi;
            unsafeAtomicAdd(&lbuf[b * S_LEN + qbase + row], lsum[r]);
        }

    float* ob = out + ((size_t)b * S_LEN + qbase) * 128;
    for (int vb = 0; vb < 4; ++vb)
        for (int r = 0; r < 16; ++r) {
            int row = (r & 3) + 8 * (r >> 2) + 4 * hi;
            unsafeAtomicAdd(&ob[(size_t)row * 128 + vb * 32 + l32], O[vb][r]);
        }
}

// ---------------- kernel 3: normalize out by row sums -------------------------
__global__ __launch_bounds__(256) void norm_kernel(float4v* __restrict__ out4,
                                                   const float* __restrict__ lbuf) {
    int i = blockIdx.x * 256 + threadIdx.x;   // 0..524287 (32 float4 per row)
    float inv = 1.0f / lbuf[i >> 5];
    float4v v = out4[i];
    v[0] *= inv; v[1] *= inv; v[2] *= inv; v[3] *= inv;
    out4[i] = v;
}

// ---------------- launch ------------------------------------------------------
extern "C" void kernel_launch(void* const* d_in, const int* in_sizes, int n_in,
                              void* d_out, int out_size, void* d_ws, size_t ws_size,
                              hipStream_t stream) {
    const float* x  = (const float*)d_in[0];
    const float* Wq = (const float*)d_in[1];
    const float* Wk = (const float*)d_in[2];
    const float* Wv = (const float*)d_in[3];
    float* out = (float*)d_out;

    _Float16* ws = (_Float16*)d_ws;
    _Float16* Qh  = ws + WS_QH;
    _Float16* Kh  = ws + WS_KH;
    _Float16* Vt  = ws + WS_VT;
    float*    lbuf = (float*)(ws + WS_L);

    qkv_proj_kernel<<<1024, 256, 0, stream>>>(x, Wq, Wk, Wv, Qh, Kh, Vt,
                                              (float4v*)out, (float4v*)lbuf);
    flash_kernel<<<dim3(S_LEN / 128, NCHUNK, NBATCH), 256, 0, stream>>>(Qh, Kh, Vt, out, lbuf);
    norm_kernel<<<2048, 256, 0, stream>>>((float4v*)out, lbuf);
}

// Round 7
// 199.082 us; speedup vs baseline: 1.0184x; 1.0184x over previous
//
#include <hip/hip_runtime.h>
#include <hip/hip_fp16.h>

typedef _Float16 half8 __attribute__((ext_vector_type(8)));
typedef float   float4v __attribute__((ext_vector_type(4)));
typedef float   float16v __attribute__((ext_vector_type(16)));

#define S_LEN 4096
#define NBATCH 4
#define NCHUNK 4
// ws layout in halves:
#define WS_QH  0          // 16384*64  (token-major [B*S][64], pre-scaled by 0.125)
#define WS_KH  1048576    // 16384*64
#define WS_VT  2097152    // 4*128*4096 (per-batch transposed [128][S])
#define WS_L   4194304    // float[16384] row sum-of-exp accumulators

// ---------------- kernel 1: QKV projection -----------------------------------
// grid 512 blocks x 256 thr. Block = 32 tokens. Wave w: m-half mh=w&1 (16 tok),
// n-half nh=w>>1 (128 out-channels as 8 nb tiles). Q gets 0.125 folded in.
// V routed through LDS -> coalesced 64B-row Vt writes. Zeroing of out/lbuf folded in.
__global__ __launch_bounds__(256) void qkv_proj_kernel(const float* __restrict__ x,
                                                       const float* __restrict__ Wq,
                                                       const float* __restrict__ Wk,
                                                       const float* __restrict__ Wv,
                                                       _Float16* __restrict__ Qh,
                                                       _Float16* __restrict__ Kh,
                                                       _Float16* __restrict__ Vt,
                                                       float4v* __restrict__ out4,
                                                       float4v* __restrict__ l4) {
    __shared__ _Float16 vs[128 * 36];   // V^T [128 vc][32 tok, pad 36]
    const int t = threadIdx.x, blk = blockIdx.x;

    // zero atomic accumulators: 524288 float4 / 512 blocks = 1024 each
    for (int i = 0; i < 4; ++i)
        out4[(size_t)blk * 1024 + t + i * 256] = (float4v){0.f, 0.f, 0.f, 0.f};
    if (t < 8) l4[blk * 8 + t] = (float4v){0.f, 0.f, 0.f, 0.f};

    const int w = t >> 6, lane = t & 63, quad = lane >> 4, n16 = lane & 15;
    const int mh = w & 1, nh = w >> 1;
    const int token0 = blk * 32, tokw = token0 + mh * 16;

    // A-frags: x rows tokw+n16 (fp32 -> fp16 inline), k = c*32 + quad*8 + j
    const float* xr = x + (size_t)(tokw + n16) * 128;
    half8 a[4];
    for (int c = 0; c < 4; ++c) {
        float4v f0 = *(const float4v*)&xr[c * 32 + quad * 8];
        float4v f1 = *(const float4v*)&xr[c * 32 + quad * 8 + 4];
        half8 h;
        h[0] = (_Float16)f0[0]; h[1] = (_Float16)f0[1];
        h[2] = (_Float16)f0[2]; h[3] = (_Float16)f0[3];
        h[4] = (_Float16)f1[0]; h[5] = (_Float16)f1[1];
        h[6] = (_Float16)f1[2]; h[7] = (_Float16)f1[3];
        a[c] = h;
    }

    float4v acc[8];
    for (int nb = 0; nb < 8; ++nb) acc[nb] = (float4v){0.f, 0.f, 0.f, 0.f};

    for (int c = 0; c < 4; ++c) {
        for (int nb = 0; nb < 8; ++nb) {
            int ocb = nh * 128 + nb * 16;           // wave-uniform base
            const float* Wsrc = (ocb < 64) ? (Wq + (size_t)(ocb + n16) * 128)
                              : (ocb < 128) ? (Wk + (size_t)(ocb - 64 + n16) * 128)
                                            : (Wv + (size_t)(ocb - 128 + n16) * 128);
            const float* wr = Wsrc + c * 32 + quad * 8;
            float4v f0 = *(const float4v*)wr;
            float4v f1 = *(const float4v*)(wr + 4);
            half8 bf;
            bf[0] = (_Float16)f0[0]; bf[1] = (_Float16)f0[1];
            bf[2] = (_Float16)f0[2]; bf[3] = (_Float16)f0[3];
            bf[4] = (_Float16)f1[0]; bf[5] = (_Float16)f1[1];
            bf[6] = (_Float16)f1[2]; bf[7] = (_Float16)f1[3];
            acc[nb] = __builtin_amdgcn_mfma_f32_16x16x32_f16(a[c], bf, acc[nb], 0, 0, 0);
        }
    }

    // C layout: col=n16 (oc), row=quad*4+r (token within 16)
    const int tokr = tokw + quad * 4;
    if (nh == 0) {
        for (int nb = 0; nb < 8; ++nb) {
            int oc = nb * 16 + n16;
            if (nb < 4) {
                for (int r = 0; r < 4; ++r)
                    Qh[(size_t)(tokr + r) * 64 + oc] = (_Float16)(acc[nb][r] * 0.125f);
            } else {
                for (int r = 0; r < 4; ++r)
                    Kh[(size_t)(tokr + r) * 64 + (oc - 64)] = (_Float16)acc[nb][r];
            }
        }
    } else {
        for (int nb = 0; nb < 8; ++nb) {
            int vc = nb * 16 + n16;
            for (int r = 0; r < 4; ++r)
                vs[vc * 36 + mh * 16 + quad * 4 + r] = (_Float16)acc[nb][r];
        }
    }
    __syncthreads();

    // coalesced V^T write-out: 128 rows x 32 tokens (64B per row)
    const int b = token0 >> 12, s0 = token0 & 4095;
    for (int i = 0; i < 2; ++i) {
        int idx = t + i * 256;          // 0..511
        int row = idx >> 2, c = idx & 3;
        *(half8*)&Vt[((size_t)b * 128 + row) * S_LEN + s0 + c * 8] =
            *(const half8*)&vs[row * 36 + c * 8];
    }
}

// ---------------- kernel 2: flash attention, 1-wave blocks, NO barriers -------
// grid 2048 x 64 thr. blockIdx.x encodes (qt, b, chunk) with (b,chunk) in the
// LOW 4 bits so co-resident blocks on a CU (stride-256 apart under round-robin
// XCD dispatch) share the same K/V stream -> L1-served.
// Wave owns 32 q rows. K frags loaded at iter top (L1-hot); V frags issued
// early, consumed after exp+P round-trip (hides L2 latency). Only Ps (wave-
// private, 4.6KB) in LDS -> no __syncthreads anywhere in the K-loop.
// 32x32x16 layouts (proven R5/R6): A m=lane&31,k=(lane>>5)*8+j; B same with n;
// C/D col=lane&31, row=(r&3)+8*(r>>2)+4*(lane>>5).
__global__ __launch_bounds__(64, 2) void flash_kernel(const _Float16* __restrict__ Qh,
                                                      const _Float16* __restrict__ Kh,
                                                      const _Float16* __restrict__ Vt,
                                                      float* __restrict__ out,
                                                      float* __restrict__ lbuf) {
    __shared__ __align__(16) _Float16 Ps[32 * 72];   // P [32q][64key], pad 72

    const int t = threadIdx.x;
    const int blk = blockIdx.x;
    const int comb = blk & 15, b = comb >> 2, chunk = comb & 3, qt = blk >> 4;
    const int l32 = t & 31, hi = t >> 5;

    const size_t q0 = (size_t)b * S_LEN + qt * 32;
    half8 aQ[4];
    for (int ks = 0; ks < 4; ++ks)
        aQ[ks] = *(const half8*)&Qh[(q0 + l32) * 64 + ks * 16 + hi * 8];

    float16v O[4];
    for (int vb = 0; vb < 4; ++vb)
        for (int r = 0; r < 16; ++r) O[vb][r] = 0.f;
    float lsum[16];
    for (int r = 0; r < 16; ++r) lsum[r] = 0.f;

    const _Float16* Kb = Kh + (size_t)b * S_LEN * 64;
    const _Float16* Vb = Vt + (size_t)b * 128 * S_LEN;

    const int kt0 = chunk * (S_LEN / 64 / NCHUNK);   // 16 iters per chunk
    const int kt1 = kt0 + (S_LEN / 64 / NCHUNK);

    for (int kt = kt0; kt < kt1; ++kt) {
        // K B-frags direct from global (L1-hot: co-resident blocks share tile)
        half8 bK[8];
        for (int knb = 0; knb < 2; ++knb)
            for (int ks = 0; ks < 4; ++ks)
                bK[knb * 4 + ks] = *(const half8*)
                    &Kb[(size_t)(kt * 64 + knb * 32 + l32) * 64 + ks * 16 + hi * 8];

        float16v S0, S1;
        for (int r = 0; r < 16; ++r) { S0[r] = 0.f; S1[r] = 0.f; }
        for (int ks = 0; ks < 4; ++ks) {
            S0 = __builtin_amdgcn_mfma_f32_32x32x16_f16(aQ[ks], bK[ks],     S0, 0, 0, 0);
            S1 = __builtin_amdgcn_mfma_f32_32x32x16_f16(aQ[ks], bK[4 + ks], S1, 0, 0, 0);
        }

        // issue V B-frag loads now; consumed after exp + Ps round-trip
        half8 v[16];
        for (int vb = 0; vb < 4; ++vb)
            for (int kb = 0; kb < 4; ++kb)
                v[vb * 4 + kb] = *(const half8*)
                    &Vb[(size_t)(vb * 32 + l32) * S_LEN + kt * 64 + kb * 16 + hi * 8];

        // exp + P store (Q pre-scaled: p = exp(S-4) = exp2(S*log2e - 4*log2e))
        for (int r = 0; r < 16; ++r) {
            float p0 = exp2f(fmaf(S0[r], 1.44269504f, -5.77078016f));
            float p1 = exp2f(fmaf(S1[r], 1.44269504f, -5.77078016f));
            lsum[r] += p0 + p1;
            int row = (r & 3) + 8 * (r >> 2) + 4 * hi;
            Ps[row * 72 + l32]      = (_Float16)p0;
            Ps[row * 72 + 32 + l32] = (_Float16)p1;
        }
        asm volatile("s_waitcnt lgkmcnt(0)" ::: "memory");   // wave-private RAW fence

        half8 aP[4];
        for (int kb = 0; kb < 4; ++kb)
            aP[kb] = *(const half8*)&Ps[l32 * 72 + kb * 16 + hi * 8];

        for (int vb = 0; vb < 4; ++vb)
            for (int kb = 0; kb < 4; ++kb)
                O[vb] = __builtin_amdgcn_mfma_f32_32x32x16_f16(aP[kb], v[vb * 4 + kb], O[vb], 0, 0, 0);
    }

    // reduce row sums across the 32 key-lanes of each half-wave
    for (int m = 1; m < 32; m <<= 1)
        for (int r = 0; r < 16; ++r)
            lsum[r] += __shfl_xor(lsum[r], m);

    const int qbase = qt * 32;
    if (l32 == 0)
        for (int r = 0; r < 16; ++r) {
            int row = (r & 3) + 8 * (r >> 2) + 4 * hi;
            unsafeAtomicAdd(&lbuf[b * S_LEN + qbase + row], lsum[r]);
        }

    float* ob = out + ((size_t)b * S_LEN + qbase) * 128;
    for (int vb = 0; vb < 4; ++vb)
        for (int r = 0; r < 16; ++r) {
            int row = (r & 3) + 8 * (r >> 2) + 4 * hi;
            unsafeAtomicAdd(&ob[(size_t)row * 128 + vb * 32 + l32], O[vb][r]);
        }
}

// ---------------- kernel 3: normalize out by row sums -------------------------
__global__ __launch_bounds__(256) void norm_kernel(float4v* __restrict__ out4,
                                                   const float* __restrict__ lbuf) {
    int i = blockIdx.x * 256 + threadIdx.x;   // 0..524287 (32 float4 per row)
    float inv = 1.0f / lbuf[i >> 5];
    float4v v = out4[i];
    v[0] *= inv; v[1] *= inv; v[2] *= inv; v[3] *= inv;
    out4[i] = v;
}

// ---------------- launch ------------------------------------------------------
extern "C" void kernel_launch(void* const* d_in, const int* in_sizes, int n_in,
                              void* d_out, int out_size, void* d_ws, size_t ws_size,
                              hipStream_t stream) {
    const float* x  = (const float*)d_in[0];
    const float* Wq = (const float*)d_in[1];
    const float* Wk = (const float*)d_in[2];
    const float* Wv = (const float*)d_in[3];
    float* out = (float*)d_out;

    _Float16* ws = (_Float16*)d_ws;
    _Float16* Qh  = ws + WS_QH;
    _Float16* Kh  = ws + WS_KH;
    _Float16* Vt  = ws + WS_VT;
    float*    lbuf = (float*)(ws + WS_L);

    qkv_proj_kernel<<<512, 256, 0, stream>>>(x, Wq, Wk, Wv, Qh, Kh, Vt,
                                             (float4v*)out, (float4v*)lbuf);
    flash_kernel<<<S_LEN / 32 * NCHUNK * NBATCH, 64, 0, stream>>>(Qh, Kh, Vt, out, lbuf);
    norm_kernel<<<2048, 256, 0, stream>>>((float4v*)out, lbuf);
}